// Round 10
// baseline (6242.914 us; speedup 1.0000x reference)
//
#include <hip/hip_runtime.h>

// SimpleLSTM B=128,T=8192,H=96. R9 post-mortem: wall = 8192 x per-step chain
// latency (~1380 cyc); adding batches/waves is free but doesn't cut wall
// (R7 4812 vs R9 4708). R10 attacks the chain: 64 blocks x 256 threads
// (4 waves), each wave processes BOTH batches of its pair interleaved
// in-stream with SHARED A-fragments:
//   - barrier syncs 4 waves (was 8): less skew/arbitration,
//   - 12 independent MFMA chains + 2 activation chains per wave: stalls
//     filled by in-wave ILP, not inter-wave round-robin,
//   - B-frag ds_reads are the first instrs after the barrier; x prefetched
//     one iter ahead; explicit 3-level select tree (masks loop-invariant).
// Layout (as R7-R9): permuted W rows => D reg r of lane (m,quad), tile mt =
// gate r (i,f,g,o) of cell 4mt+quad; all 16 D cols identical. Wave wv owns
// tiles 6wv..6wv+5; lane updates cell 24wv+4*(m%6)+quad for both batches;
// wv3 owns the y-tile (row0=w_out); y staged in LDS rings flushed 128-at-a-
// time (wv0 -> batch0, wv1 -> batch1). x fully staged in LDS. exp2-domain
// prescale (weights/biases x log2e, g-rows x 2log2e). All per-thread state
// NAMED SCALARS (R5 PromoteAlloca lesson); A-frags pinned via asm.

#define T_LEN 8192
#define H_DIM 96
#define NTHR  256   // 4 waves
#define CHUNK 128
#define LOG2E 1.44269504f

typedef float    f32x4 __attribute__((ext_vector_type(4)));
typedef _Float16 half8 __attribute__((ext_vector_type(8)));

#define MFMA16(A, B, C)                                                        \
    __builtin_amdgcn_mfma_f32_16x16x32_f16(__builtin_bit_cast(half8, (A)),     \
                                           __builtin_bit_cast(half8, (B)),     \
                                           (C), 0, 0, 0)

__device__ __forceinline__ float sig2(float s) {   // sigmoid, s = log2e*pre
    return __builtin_amdgcn_rcpf(1.0f + __builtin_amdgcn_exp2f(-s));
}
__device__ __forceinline__ float tanh2(float sg) { // tanh, sg = 2log2e*pre
    return 1.0f - 2.0f * __builtin_amdgcn_rcpf(1.0f + __builtin_amdgcn_exp2f(sg));
}

__device__ __forceinline__ f32x4 load_afrag(const float* __restrict__ w_hh,
                                            const float* __restrict__ w_out,
                                            int mt, int kt, int m, int quad) {
    half8 f;
    if (mt < 24) {
        const int r = m & 3;                       // gate: 0=i 1=f 2=g 3=o
        const float scale = (r == 2) ? 2.0f * LOG2E : LOG2E;
        const int orig = r * 96 + 4 * mt + (m >> 2);
        const float* src = w_hh + orig * H_DIM + kt * 32 + quad * 8;
        #pragma unroll
        for (int jj = 0; jj < 8; ++jj) f[jj] = (_Float16)(scale * src[jj]);
    } else {  // y tile: row 0 = w_out (unscaled), rows 1..15 = 0
        #pragma unroll
        for (int jj = 0; jj < 8; ++jj)
            f[jj] = (m == 0) ? (_Float16)w_out[kt * 32 + quad * 8 + jj]
                             : (_Float16)0.0f;
    }
    return __builtin_bit_cast(f32x4, f);
}

__global__ __launch_bounds__(NTHR, 1) void lstm_mfma7_kernel(
    const float* __restrict__ x,      // [B, T]
    const float* __restrict__ w_ih,   // [4H]
    const float* __restrict__ w_hh,   // [4H, H]
    const float* __restrict__ b_ih,   // [4H]
    const float* __restrict__ b_hh,   // [4H]
    const float* __restrict__ w_out,  // [H]
    const float* __restrict__ b_out,  // [1]
    float* __restrict__ y)            // [B, T]
{
    const int tid  = threadIdx.x;
    const int wv   = tid >> 6;
    const int lane = tid & 63;
    const int m    = lane & 15;
    const int quad = lane >> 4;
    const int bat0 = 2 * blockIdx.x;  // batches bat0, bat0+1

    __shared__ __align__(16) _Float16 h_s[2][2][H_DIM];   // [bat][buf][cell]
    __shared__ __align__(16) float    y_buf[2][2][CHUNK]; // [bat][ring][i]
    __shared__ __align__(16) float    x_s[2][T_LEN];      // 64 KB

    // ---- stage both x rows (contiguous: batches bat0, bat0+1)
    const float* xbase = x + (size_t)bat0 * T_LEN;
    float* xs_flat = &x_s[0][0];
    for (int i = tid * 4; i < 2 * T_LEN; i += NTHR * 4)
        *reinterpret_cast<f32x4*>(&xs_flat[i]) =
            *reinterpret_cast<const f32x4*>(&xbase[i]);

    // ---- A fragments (SHARED by both batches; named, pinned)
    const int mt0 = 6 * wv;
    f32x4 af00 = load_afrag(w_hh, w_out, mt0 + 0, 0, m, quad);
    f32x4 af01 = load_afrag(w_hh, w_out, mt0 + 0, 1, m, quad);
    f32x4 af02 = load_afrag(w_hh, w_out, mt0 + 0, 2, m, quad);
    f32x4 af10 = load_afrag(w_hh, w_out, mt0 + 1, 0, m, quad);
    f32x4 af11 = load_afrag(w_hh, w_out, mt0 + 1, 1, m, quad);
    f32x4 af12 = load_afrag(w_hh, w_out, mt0 + 1, 2, m, quad);
    f32x4 af20 = load_afrag(w_hh, w_out, mt0 + 2, 0, m, quad);
    f32x4 af21 = load_afrag(w_hh, w_out, mt0 + 2, 1, m, quad);
    f32x4 af22 = load_afrag(w_hh, w_out, mt0 + 2, 2, m, quad);
    f32x4 af30 = load_afrag(w_hh, w_out, mt0 + 3, 0, m, quad);
    f32x4 af31 = load_afrag(w_hh, w_out, mt0 + 3, 1, m, quad);
    f32x4 af32 = load_afrag(w_hh, w_out, mt0 + 3, 2, m, quad);
    f32x4 af40 = load_afrag(w_hh, w_out, mt0 + 4, 0, m, quad);
    f32x4 af41 = load_afrag(w_hh, w_out, mt0 + 4, 1, m, quad);
    f32x4 af42 = load_afrag(w_hh, w_out, mt0 + 4, 2, m, quad);
    f32x4 af50 = load_afrag(w_hh, w_out, mt0 + 5, 0, m, quad);
    f32x4 af51 = load_afrag(w_hh, w_out, mt0 + 5, 1, m, quad);
    f32x4 af52 = load_afrag(w_hh, w_out, mt0 + 5, 2, m, quad);
    f32x4 afy0 = {0.f, 0.f, 0.f, 0.f};
    f32x4 afy1 = {0.f, 0.f, 0.f, 0.f};
    f32x4 afy2 = {0.f, 0.f, 0.f, 0.f};
    if (wv == 3) {
        afy0 = load_afrag(w_hh, w_out, 24, 0, m, quad);
        afy1 = load_afrag(w_hh, w_out, 24, 1, m, quad);
        afy2 = load_afrag(w_hh, w_out, 24, 2, m, quad);
    }
    f32x4 zero4 = {0.f, 0.f, 0.f, 0.f};
    asm volatile("" : "+v"(af00), "+v"(af01), "+v"(af02), "+v"(af10),
                      "+v"(af11), "+v"(af12), "+v"(af20));
    asm volatile("" : "+v"(af21), "+v"(af22), "+v"(af30), "+v"(af31),
                      "+v"(af32), "+v"(af40), "+v"(af41));
    asm volatile("" : "+v"(af42), "+v"(af50), "+v"(af51), "+v"(af52),
                      "+v"(afy0), "+v"(afy1), "+v"(afy2), "+v"(zero4));

    // ---- per-lane cell params (shared across batches; exp2-prescaled)
    const int sel  = (m >= 12) ? (m - 12) : ((m >= 6) ? (m - 6) : m);
    const int cell = 24 * wv + 4 * sel + quad;
    const float bias_i = LOG2E * (b_ih[0 * H_DIM + cell] + b_hh[0 * H_DIM + cell]);
    const float bias_f = LOG2E * (b_ih[1 * H_DIM + cell] + b_hh[1 * H_DIM + cell]);
    const float bias_g = 2.0f * LOG2E * (b_ih[2 * H_DIM + cell] + b_hh[2 * H_DIM + cell]);
    const float bias_o = LOG2E * (b_ih[3 * H_DIM + cell] + b_hh[3 * H_DIM + cell]);
    const float wih_i  = LOG2E * w_ih[0 * H_DIM + cell];
    const float wih_f  = LOG2E * w_ih[1 * H_DIM + cell];
    const float wih_g  = 2.0f * LOG2E * w_ih[2 * H_DIM + cell];
    const float wih_o  = LOG2E * w_ih[3 * H_DIM + cell];
    const float bout   = b_out[0];
    float cA = 0.f, cB = 0.f;
    if (tid < H_DIM)            h_s[0][0][tid] = (_Float16)0.0f;
    else if (tid < 2 * H_DIM)   h_s[1][0][tid - H_DIM] = (_Float16)0.0f;
    __syncthreads();

    float*       yrow0 = y + (size_t)bat0 * T_LEN;
    float*       yrow1 = yrow0 + T_LEN;

    float xa_n = x_s[0][0], xb_n = x_s[1][0];

    // iter it: reads h_{it-1}; makes h_it; y tile -> y_{it-1}.
    for (int it = 0; it <= T_LEN + 1; ++it) {
        const int p = it & 1;
        const float xa_c = xa_n, xb_c = xb_n;

        f32x4 a0, a1, a2, a3, a4, a5, ay;   // batch0 accs
        f32x4 b0, b1, b2, b3, b4, b5, by;   // batch1 accs

        if (it <= T_LEN) {
            // B-frag reads FIRST after barrier (critical path)
            const f32x4 ha0 = *reinterpret_cast<const f32x4*>(&h_s[0][p][quad * 8]);
            const f32x4 ha1 = *reinterpret_cast<const f32x4*>(&h_s[0][p][32 + quad * 8]);
            const f32x4 ha2 = *reinterpret_cast<const f32x4*>(&h_s[0][p][64 + quad * 8]);
            const f32x4 hb0 = *reinterpret_cast<const f32x4*>(&h_s[1][p][quad * 8]);
            const f32x4 hb1 = *reinterpret_cast<const f32x4*>(&h_s[1][p][32 + quad * 8]);
            const f32x4 hb2 = *reinterpret_cast<const f32x4*>(&h_s[1][p][64 + quad * 8]);
            // x prefetch for it+1 (latency hidden behind MFMAs)
            const int nx = (it + 1 < T_LEN) ? (it + 1) : (T_LEN - 1);
            xa_n = x_s[0][nx];
            xb_n = x_s[1][nx];

            a0 = MFMA16(af00, ha0, zero4);  b0 = MFMA16(af00, hb0, zero4);
            a1 = MFMA16(af10, ha0, zero4);  b1 = MFMA16(af10, hb0, zero4);
            a2 = MFMA16(af20, ha0, zero4);  b2 = MFMA16(af20, hb0, zero4);
            a3 = MFMA16(af30, ha0, zero4);  b3 = MFMA16(af30, hb0, zero4);
            a4 = MFMA16(af40, ha0, zero4);  b4 = MFMA16(af40, hb0, zero4);
            a5 = MFMA16(af50, ha0, zero4);  b5 = MFMA16(af50, hb0, zero4);
            a0 = MFMA16(af01, ha1, a0);     b0 = MFMA16(af01, hb1, b0);
            a1 = MFMA16(af11, ha1, a1);     b1 = MFMA16(af11, hb1, b1);
            a2 = MFMA16(af21, ha1, a2);     b2 = MFMA16(af21, hb1, b2);
            a3 = MFMA16(af31, ha1, a3);     b3 = MFMA16(af31, hb1, b3);
            a4 = MFMA16(af41, ha1, a4);     b4 = MFMA16(af41, hb1, b4);
            a5 = MFMA16(af51, ha1, a5);     b5 = MFMA16(af51, hb1, b5);
            a0 = MFMA16(af02, ha2, a0);     b0 = MFMA16(af02, hb2, b0);
            a1 = MFMA16(af12, ha2, a1);     b1 = MFMA16(af12, hb2, b1);
            a2 = MFMA16(af22, ha2, a2);     b2 = MFMA16(af22, hb2, b2);
            a3 = MFMA16(af32, ha2, a3);     b3 = MFMA16(af32, hb2, b3);
            a4 = MFMA16(af42, ha2, a4);     b4 = MFMA16(af42, hb2, b4);
            a5 = MFMA16(af52, ha2, a5);     b5 = MFMA16(af52, hb2, b5);
            if (wv == 3) {
                ay = MFMA16(afy0, ha0, zero4);  by = MFMA16(afy0, hb0, zero4);
                ay = MFMA16(afy1, ha1, ay);     by = MFMA16(afy1, hb1, by);
                ay = MFMA16(afy2, ha2, ay);     by = MFMA16(afy2, hb2, by);
                if (lane == 0 && it > 0) {
                    const int ring = ((it - 1) >> 7) & 1;
                    const int slot = (it - 1) & (CHUNK - 1);
                    y_buf[0][ring][slot] = ay.x + bout;
                    y_buf[1][ring][slot] = by.x + bout;
                }
            }
        }

        // ring flush: chunk [it-1-CHUNK, it-1) complete; wv0->bat0, wv1->bat1
        if ((it & (CHUNK - 1)) == 1 && it > 1 && wv < 2 && lane < 32) {
            const int base = it - 1 - CHUNK;
            const int pb = (base >> 7) & 1;
            const f32x4 v =
                *reinterpret_cast<const f32x4*>(&y_buf[wv][pb][lane * 4]);
            float* yr = (wv == 0) ? yrow0 : yrow1;
            *reinterpret_cast<f32x4*>(&yr[base + lane * 4]) = v;
        }

        if (it < T_LEN) {
            // 3-level select tree (compare masks loop-invariant)
            const f32x4 gA01 = (sel == 1) ? a1 : a0;
            const f32x4 gA23 = (sel == 3) ? a3 : a2;
            const f32x4 gA45 = (sel == 5) ? a5 : a4;
            const f32x4 gAlo = (sel >= 2) ? gA23 : gA01;
            const f32x4 gA   = (sel >= 4) ? gA45 : gAlo;
            const f32x4 gB01 = (sel == 1) ? b1 : b0;
            const f32x4 gB23 = (sel == 3) ? b3 : b2;
            const f32x4 gB45 = (sel == 5) ? b5 : b4;
            const f32x4 gBlo = (sel >= 2) ? gB23 : gB01;
            const f32x4 gB   = (sel >= 4) ? gB45 : gBlo;

            const float sA0 = gA.x + fmaf(xa_c, wih_i, bias_i);
            const float sB0 = gB.x + fmaf(xb_c, wih_i, bias_i);
            const float sA1 = gA.y + fmaf(xa_c, wih_f, bias_f);
            const float sB1 = gB.y + fmaf(xb_c, wih_f, bias_f);
            const float sA2 = gA.z + fmaf(xa_c, wih_g, bias_g);
            const float sB2 = gB.z + fmaf(xb_c, wih_g, bias_g);
            const float sA3 = gA.w + fmaf(xa_c, wih_o, bias_o);
            const float sB3 = gB.w + fmaf(xb_c, wih_o, bias_o);
            const float igA = sig2(sA0),  igB = sig2(sB0);
            const float fgA = sig2(sA1),  fgB = sig2(sB1);
            const float ggA = tanh2(sA2), ggB = tanh2(sB2);
            const float ogA = sig2(sA3),  ogB = sig2(sB3);
            cA = fmaf(fgA, cA, igA * ggA);
            cB = fmaf(fgB, cB, igB * ggB);
            const float hA = ogA * tanh2(2.0f * LOG2E * cA);
            const float hB = ogB * tanh2(2.0f * LOG2E * cB);
            if (m < 6) {
                h_s[0][p ^ 1][cell] = (_Float16)hA;
                h_s[1][p ^ 1][cell] = (_Float16)hB;
            }
        }
        __syncthreads();  // h_s[.][p^1] + y_buf ready
    }
}

extern "C" void kernel_launch(void* const* d_in, const int* in_sizes, int n_in,
                              void* d_out, int out_size, void* d_ws, size_t ws_size,
                              hipStream_t stream) {
    const float* x     = (const float*)d_in[0];
    const float* w_ih  = (const float*)d_in[1];
    const float* w_hh  = (const float*)d_in[2];
    const float* b_ih  = (const float*)d_in[3];
    const float* b_hh  = (const float*)d_in[4];
    const float* w_out = (const float*)d_in[5];
    const float* b_out = (const float*)d_in[6];
    float* y = (float*)d_out;

    const int NBLK = 64;  // 2 batches per block
    lstm_mfma7_kernel<<<dim3(NBLK), dim3(NTHR), 0, stream>>>(
        x, w_ih, w_hh, b_ih, b_hh, w_out, b_out, y);
}

// Round 11
// 4815.665 us; speedup vs baseline: 1.2964x; 1.2964x over previous
//
#include <hip/hip_runtime.h>

// SimpleLSTM B=128,T=8192,H=96. R10 post-mortem: in-wave batch-merge
// serialized the two batches in one issue stream (6243 us, worse). Base is
// R9 (4708 us): 64 blocks x 512 threads, waves 0-3 = batch 2b, waves 4-7 =
// batch 2b+1 (independent waves per SIMD interleave stalls). R11 = R9 +
// issue trims only:
//   - x stored interleaved x_s[t][2] -> ONE ds_read_b64 serves both groups
//   - 2-step unroll with literal p (no per-step parity/index arith)
//   - h written per-batch as soon as computed (drains before barrier)
// Layout (R7-R9): permuted W rows => D reg r of lane (m,quad), tile mt =
// gate r (i,f,g,o) of cell 4mt+quad; all 16 D cols identical. Wave wv owns
// tiles 6wv..6wv+5; lane updates cell 24wv+4*(m%6)+quad; wv3 owns y-tile
// (row0=w_out); y staged in LDS ring flushed 128-at-a-time by wv0/wv1.
// exp2-domain prescale; NAMED SCALARS only (R5 PromoteAlloca lesson).

#define T_LEN 8192
#define H_DIM 96
#define NTHR  512   // 8 waves: 2 groups x 4
#define CHUNK 128
#define LOG2E 1.44269504f

typedef float    f32x2 __attribute__((ext_vector_type(2)));
typedef float    f32x4 __attribute__((ext_vector_type(4)));
typedef _Float16 half8 __attribute__((ext_vector_type(8)));

#define MFMA16(A, B, C)                                                        \
    __builtin_amdgcn_mfma_f32_16x16x32_f16(__builtin_bit_cast(half8, (A)),     \
                                           __builtin_bit_cast(half8, (B)),     \
                                           (C), 0, 0, 0)

__device__ __forceinline__ float sig2(float s) {   // sigmoid, s = log2e*pre
    return __builtin_amdgcn_rcpf(1.0f + __builtin_amdgcn_exp2f(-s));
}
__device__ __forceinline__ float tanh2(float sg) { // tanh, sg = 2log2e*pre
    return 1.0f - 2.0f * __builtin_amdgcn_rcpf(1.0f + __builtin_amdgcn_exp2f(sg));
}

__device__ __forceinline__ f32x4 load_afrag(const float* __restrict__ w_hh,
                                            const float* __restrict__ w_out,
                                            int mt, int kt, int m, int quad) {
    half8 f;
    if (mt < 24) {
        const int r = m & 3;                       // gate: 0=i 1=f 2=g 3=o
        const float scale = (r == 2) ? 2.0f * LOG2E : LOG2E;
        const int orig = r * 96 + 4 * mt + (m >> 2);
        const float* src = w_hh + orig * H_DIM + kt * 32 + quad * 8;
        #pragma unroll
        for (int jj = 0; jj < 8; ++jj) f[jj] = (_Float16)(scale * src[jj]);
    } else {  // y tile: row 0 = w_out (unscaled), rows 1..15 = 0
        #pragma unroll
        for (int jj = 0; jj < 8; ++jj)
            f[jj] = (m == 0) ? (_Float16)w_out[kt * 32 + quad * 8 + jj]
                             : (_Float16)0.0f;
    }
    return __builtin_bit_cast(f32x4, f);
}

__global__ __launch_bounds__(NTHR, 2) void lstm_mfma8_kernel(
    const float* __restrict__ x,      // [B, T]
    const float* __restrict__ w_ih,   // [4H]
    const float* __restrict__ w_hh,   // [4H, H]
    const float* __restrict__ b_ih,   // [4H]
    const float* __restrict__ b_hh,   // [4H]
    const float* __restrict__ w_out,  // [H]
    const float* __restrict__ b_out,  // [1]
    float* __restrict__ y)            // [B, T]
{
    const int tid  = threadIdx.x;
    const int wave = tid >> 6;
    const int grp  = wave >> 2;       // 0/1: which batch of the pair
    const int wv   = wave & 3;        // role within group
    const int lane = tid & 63;
    const int m    = lane & 15;
    const int quad = lane >> 4;
    const int bat  = 2 * blockIdx.x + grp;

    __shared__ __align__(16) _Float16 h_s[2][2][H_DIM];   // [grp][buf][cell]
    __shared__ __align__(16) float    y_buf[2][2][CHUNK]; // [grp][ring][i]
    __shared__ __align__(16) float    x_s[T_LEN][2];      // interleaved, 64 KB

    const float* xrow  = x + (size_t)bat * T_LEN;
    const float* xrow0 = x + (size_t)(2 * blockIdx.x) * T_LEN;
    const float* xrow1 = xrow0 + T_LEN;
    float*       yrow  = y + (size_t)bat * T_LEN;
    (void)xrow;

    // ---- stage x interleaved: x_s[t] = {x0[t], x1[t]} (one-time)
    for (int t = tid; t < T_LEN; t += NTHR) {
        x_s[t][0] = xrow0[t];
        x_s[t][1] = xrow1[t];
    }

    // ---- A fragments (named, pinned). wv owns tiles 6wv..6wv+5; wv3: +y tile
    const int mt0 = 6 * wv;
    f32x4 af00 = load_afrag(w_hh, w_out, mt0 + 0, 0, m, quad);
    f32x4 af01 = load_afrag(w_hh, w_out, mt0 + 0, 1, m, quad);
    f32x4 af02 = load_afrag(w_hh, w_out, mt0 + 0, 2, m, quad);
    f32x4 af10 = load_afrag(w_hh, w_out, mt0 + 1, 0, m, quad);
    f32x4 af11 = load_afrag(w_hh, w_out, mt0 + 1, 1, m, quad);
    f32x4 af12 = load_afrag(w_hh, w_out, mt0 + 1, 2, m, quad);
    f32x4 af20 = load_afrag(w_hh, w_out, mt0 + 2, 0, m, quad);
    f32x4 af21 = load_afrag(w_hh, w_out, mt0 + 2, 1, m, quad);
    f32x4 af22 = load_afrag(w_hh, w_out, mt0 + 2, 2, m, quad);
    f32x4 af30 = load_afrag(w_hh, w_out, mt0 + 3, 0, m, quad);
    f32x4 af31 = load_afrag(w_hh, w_out, mt0 + 3, 1, m, quad);
    f32x4 af32 = load_afrag(w_hh, w_out, mt0 + 3, 2, m, quad);
    f32x4 af40 = load_afrag(w_hh, w_out, mt0 + 4, 0, m, quad);
    f32x4 af41 = load_afrag(w_hh, w_out, mt0 + 4, 1, m, quad);
    f32x4 af42 = load_afrag(w_hh, w_out, mt0 + 4, 2, m, quad);
    f32x4 af50 = load_afrag(w_hh, w_out, mt0 + 5, 0, m, quad);
    f32x4 af51 = load_afrag(w_hh, w_out, mt0 + 5, 1, m, quad);
    f32x4 af52 = load_afrag(w_hh, w_out, mt0 + 5, 2, m, quad);
    f32x4 afy0 = {0.f, 0.f, 0.f, 0.f};
    f32x4 afy1 = {0.f, 0.f, 0.f, 0.f};
    f32x4 afy2 = {0.f, 0.f, 0.f, 0.f};
    if (wv == 3) {
        afy0 = load_afrag(w_hh, w_out, 24, 0, m, quad);
        afy1 = load_afrag(w_hh, w_out, 24, 1, m, quad);
        afy2 = load_afrag(w_hh, w_out, 24, 2, m, quad);
    }
    f32x4 zero4 = {0.f, 0.f, 0.f, 0.f};
    asm volatile("" : "+v"(af00), "+v"(af01), "+v"(af02), "+v"(af10),
                      "+v"(af11), "+v"(af12), "+v"(af20));
    asm volatile("" : "+v"(af21), "+v"(af22), "+v"(af30), "+v"(af31),
                      "+v"(af32), "+v"(af40), "+v"(af41));
    asm volatile("" : "+v"(af42), "+v"(af50), "+v"(af51), "+v"(af52),
                      "+v"(afy0), "+v"(afy1), "+v"(afy2), "+v"(zero4));

    // ---- per-lane cell params (exp2-domain prescaled)
    const int sel  = (m >= 12) ? (m - 12) : ((m >= 6) ? (m - 6) : m);
    const int cell = 24 * wv + 4 * sel + quad;
    const float bias_i = LOG2E * (b_ih[0 * H_DIM + cell] + b_hh[0 * H_DIM + cell]);
    const float bias_f = LOG2E * (b_ih[1 * H_DIM + cell] + b_hh[1 * H_DIM + cell]);
    const float bias_g = 2.0f * LOG2E * (b_ih[2 * H_DIM + cell] + b_hh[2 * H_DIM + cell]);
    const float bias_o = LOG2E * (b_ih[3 * H_DIM + cell] + b_hh[3 * H_DIM + cell]);
    const float wih_i  = LOG2E * w_ih[0 * H_DIM + cell];
    const float wih_f  = LOG2E * w_ih[1 * H_DIM + cell];
    const float wih_g  = 2.0f * LOG2E * w_ih[2 * H_DIM + cell];
    const float wih_o  = LOG2E * w_ih[3 * H_DIM + cell];
    const float bout   = b_out[0];
    float c = 0.f;
    if ((tid & 255) < H_DIM) h_s[grp][0][tid & 255] = (_Float16)0.0f;
    __syncthreads();

    float* yrow_flush = y + (size_t)(2 * blockIdx.x + (wv & 1)) * T_LEN;

    // one step; p is a LITERAL at each call site (2x unroll below)
#define STEP(IT, P)                                                            \
    {                                                                          \
        const int it = (IT);                                                   \
        f32x4 acc0, acc1, acc2, acc3, acc4, acc5, accy;                        \
        float x_cur = 0.f;                                                     \
        if (it < T_LEN)                                                        \
            x_cur = (*reinterpret_cast<const f32x2*>(&x_s[it][0]))[grp];       \
        if (it <= T_LEN) {                                                     \
            const f32x4 b0 = *reinterpret_cast<const f32x4*>(&h_s[grp][P][quad * 8]);        \
            const f32x4 b1 = *reinterpret_cast<const f32x4*>(&h_s[grp][P][32 + quad * 8]);   \
            const f32x4 b2 = *reinterpret_cast<const f32x4*>(&h_s[grp][P][64 + quad * 8]);   \
            acc0 = MFMA16(af00, b0, zero4);                                    \
            acc1 = MFMA16(af10, b0, zero4);                                    \
            acc2 = MFMA16(af20, b0, zero4);                                    \
            acc3 = MFMA16(af30, b0, zero4);                                    \
            acc4 = MFMA16(af40, b0, zero4);                                    \
            acc5 = MFMA16(af50, b0, zero4);                                    \
            acc0 = MFMA16(af01, b1, acc0);                                     \
            acc1 = MFMA16(af11, b1, acc1);                                     \
            acc2 = MFMA16(af21, b1, acc2);                                     \
            acc3 = MFMA16(af31, b1, acc3);                                     \
            acc4 = MFMA16(af41, b1, acc4);                                     \
            acc5 = MFMA16(af51, b1, acc5);                                     \
            acc0 = MFMA16(af02, b2, acc0);                                     \
            acc1 = MFMA16(af12, b2, acc1);                                     \
            acc2 = MFMA16(af22, b2, acc2);                                     \
            acc3 = MFMA16(af32, b2, acc3);                                     \
            acc4 = MFMA16(af42, b2, acc4);                                     \
            acc5 = MFMA16(af52, b2, acc5);                                     \
            if (wv == 3) {                                                     \
                accy = MFMA16(afy0, b0, zero4);                                \
                accy = MFMA16(afy1, b1, accy);                                 \
                accy = MFMA16(afy2, b2, accy);                                 \
                if (lane == 0 && it > 0)                                       \
                    y_buf[grp][((it - 1) >> 7) & 1][(it - 1) & (CHUNK - 1)] =  \
                        accy.x + bout;                                         \
            }                                                                  \
        }                                                                      \
        if ((it & (CHUNK - 1)) == 1 && it > 1 && wv < 2 && lane < 32) {        \
            const int base_ = it - 1 - CHUNK;                                  \
            const int pb = (base_ >> 7) & 1;                                   \
            const f32x4 v =                                                    \
                *reinterpret_cast<const f32x4*>(&y_buf[wv][pb][lane * 4]);     \
            *reinterpret_cast<f32x4*>(&yrow_flush[base_ + lane * 4]) = v;      \
        }                                                                      \
        if (it < T_LEN) {                                                      \
            const f32x4 g01 = (sel == 1) ? acc1 : acc0;                        \
            const f32x4 g23 = (sel == 3) ? acc3 : acc2;                        \
            const f32x4 g45 = (sel == 5) ? acc5 : acc4;                        \
            const f32x4 glo = (sel >= 2) ? g23 : g01;                          \
            const f32x4 g4  = (sel >= 4) ? g45 : glo;                          \
            const float s0 = g4.x + fmaf(x_cur, wih_i, bias_i);                \
            const float s1 = g4.y + fmaf(x_cur, wih_f, bias_f);                \
            const float s2 = g4.z + fmaf(x_cur, wih_g, bias_g);                \
            const float s3 = g4.w + fmaf(x_cur, wih_o, bias_o);                \
            const float ig = sig2(s0);                                         \
            const float fg = sig2(s1);                                         \
            const float gg = tanh2(s2);                                        \
            const float og = sig2(s3);                                         \
            c = fmaf(fg, c, ig * gg);                                          \
            const float h = og * tanh2(2.0f * LOG2E * c);                      \
            if (m < 6) h_s[grp][(P) ^ 1][cell] = (_Float16)h;                  \
        }                                                                      \
        __syncthreads();                                                       \
    }

    // iters 0..T_LEN+1 (=8193), in pairs with literal parity
    for (int base = 0; base <= T_LEN; base += 2) {
        STEP(base, 0)
        STEP(base + 1, 1)
    }
#undef STEP
}

extern "C" void kernel_launch(void* const* d_in, const int* in_sizes, int n_in,
                              void* d_out, int out_size, void* d_ws, size_t ws_size,
                              hipStream_t stream) {
    const float* x     = (const float*)d_in[0];
    const float* w_ih  = (const float*)d_in[1];
    const float* w_hh  = (const float*)d_in[2];
    const float* b_ih  = (const float*)d_in[3];
    const float* b_hh  = (const float*)d_in[4];
    const float* w_out = (const float*)d_in[5];
    const float* b_out = (const float*)d_in[6];
    float* y = (float*)d_out;

    const int NBLK = 64;  // 2 batches per block
    lstm_mfma8_kernel<<<dim3(NBLK), dim3(NTHR), 0, stream>>>(
        x, w_ih, w_hh, b_ih, b_hh, w_out, b_out, y);
}